// Round 4
// baseline (1830.081 us; speedup 1.0000x reference)
//
#include <hip/hip_runtime.h>
#include <cmath>

#define EPS 1e-5f
#define TAU 0.3f

// Problem constants (fixed instance)
#define Bn 16
#define Dn 256
#define Tn 4096
#define Kn 2048

typedef unsigned short ushort_t;
typedef __attribute__((ext_vector_type(8))) short bf16x8;
typedef __attribute__((ext_vector_type(4))) float f32x4;

__device__ __forceinline__ unsigned short f2bf(float v, float& back) {
    union { float f; unsigned u; } a; a.f = v;
    unsigned r = a.u + 0x7fffu + ((a.u >> 16) & 1u);   // RNE
    unsigned short h = (unsigned short)(r >> 16);
    union { float f; unsigned u; } b; b.u = ((unsigned)h) << 16;
    back = b.f;
    return h;
}

// bf16 rounded UP in value (>= v): safe upper bound for second-best scores.
__device__ __forceinline__ unsigned short bf16_up(float v) {
    union { float f; unsigned u; } a; a.f = v;
    if ((int)a.u >= 0) return (unsigned short)((a.u + 0xffffu) >> 16);
    return (unsigned short)(a.u >> 16);   // negative: truncate -> toward 0 -> up
}

#define GLOAD_LDS16(gp, lp) __builtin_amdgcn_global_load_lds( \
    (const __attribute__((address_space(1))) unsigned int*)(gp), \
    (__attribute__((address_space(3))) unsigned int*)(lp), 16, 0, 0)

// ---------------------------------------------------------------------------
// Kernel 1: prep — emb = es / max(usage,eps); bf16 hi/mid planes; bias = 0.5|e|^2
// ---------------------------------------------------------------------------
__global__ __launch_bounds__(256) void prep_kernel(
    const float* __restrict__ es, const float* __restrict__ usage,
    float* __restrict__ emb, ushort_t* __restrict__ eh,
    ushort_t* __restrict__ em, float* __restrict__ bias,
    int* __restrict__ counter)
{
    const int k = blockIdx.x;
    const int d = threadIdx.x;
    const float inv = 1.0f / fmaxf(usage[k], EPS);
    const float v = es[(size_t)k * Dn + d] * inv;
    emb[(size_t)k * Dn + d] = v;
    float hb, dummy;
    unsigned short h = f2bf(v, hb);
    eh[(size_t)k * Dn + d] = h;
    em[(size_t)k * Dn + d] = f2bf(v - hb, dummy);
    float sq = v * v;
    #pragma unroll
    for (int off = 32; off > 0; off >>= 1) sq += __shfl_down(sq, off, 64);
    __shared__ float wsum[4];
    const int lane = threadIdx.x & 63;
    const int wv = threadIdx.x >> 6;
    if (lane == 0) wsum[wv] = sq;
    __syncthreads();
    if (threadIdx.x == 0) {
        bias[k] = 0.5f * (wsum[0] + wsum[1] + wsum[2] + wsum[3]);
        if (k == 0) *counter = 0;
    }
}

// ---------------------------------------------------------------------------
// Kernel 2: xsplit — x[b][d][t] fp32 -> xh[b][t][d] bf16 (hi plane only).
// Full-D tile (256 d x 16 t) so writes are contiguous 512 B per t-row.
// ---------------------------------------------------------------------------
__global__ __launch_bounds__(256) void xsplit_kernel(
    const float* __restrict__ x, ushort_t* __restrict__ xh)
{
    __shared__ float tile[256 * 17];
    const int t0 = blockIdx.x * 16;
    const int b  = blockIdx.y;
    const int tid = threadIdx.x;

    // read: thread = d row; 16 floats along t (4x float4), scalar LDS stores
    {
        const float* src = x + ((size_t)(b * Dn + tid)) * Tn + t0;
        float* row = &tile[tid * 17];
        #pragma unroll
        for (int q = 0; q < 4; ++q) {
            const float4 a = *(const float4*)(src + q * 4);
            row[q * 4 + 0] = a.x; row[q * 4 + 1] = a.y;
            row[q * 4 + 2] = a.z; row[q * 4 + 3] = a.w;
        }
    }
    __syncthreads();
    // write: tq = t row (16), dq covers d in 16B chunks; fully coalesced
    {
        const int tq = tid >> 4, dq = tid & 15;
        #pragma unroll
        for (int u = 0; u < 2; ++u) {
            const int c = dq + u * 16;          // chunk 0..31 -> d = c*8..c*8+7
            unsigned wh[4];
            #pragma unroll
            for (int i = 0; i < 4; ++i) {
                const float a = tile[(c * 8 + 2 * i) * 17 + tq];
                const float g = tile[(c * 8 + 2 * i + 1) * 17 + tq];
                float hb; float dummy;
                const unsigned short h0 = f2bf(a, hb);
                const unsigned short h1 = f2bf(g, dummy);
                wh[i] = (unsigned)h0 | ((unsigned)h1 << 16);
            }
            const size_t o = ((size_t)(b * Tn + t0 + tq)) * Dn + c * 8;
            *(uint4*)(xh + o) = make_uint4(wh[0], wh[1], wh[2], wh[3]);
        }
    }
}

// ---------------------------------------------------------------------------
// Kernel 3: 2-product MFMA GEMM + top-2 argmax.  s ~= xh.(eh+em).
// Block 256thr/4 waves (2x2), wave-tile 64t x 64k, block tile 128t x 128k/kc,
// KSPLIT=8 (256 k per block, 2 kc passes), BK=32. Writes packed (s1,s2up,k)
// 8 B records, 16 per point (ks*2+kc).
// ---------------------------------------------------------------------------
__global__ __launch_bounds__(256, 3) void gemm_argmax(
    const ushort_t* __restrict__ xh, const ushort_t* __restrict__ eh,
    const ushort_t* __restrict__ em, const float* __restrict__ bias,
    uint2* __restrict__ rec)
{
    __shared__ ushort_t AhS[128 * 32];   // 8 KB  [t][d32]
    __shared__ ushort_t BhS[128 * 32];   // 8 KB  [k][d32]
    __shared__ ushort_t BmS[128 * 32];   // 8 KB
    __shared__ float rS1[2][128];
    __shared__ float rS2[2][128];
    __shared__ int   rKx[2][128];

    const int bid   = blockIdx.x;
    const int xcd   = bid & 7;
    const int ks    = (bid >> 3) & 7;
    const int tilid = bid >> 6;
    const int gtile = tilid * 8 + xcd;   // ks-siblings of one (b,tt) share an XCD
    const int b     = gtile >> 5;
    const int tt    = gtile & 31;
    const int t0    = tt << 7;
    const int kbase = ks << 8;

    const int tid  = threadIdx.x;
    const int lane = tid & 63;
    const int wid  = tid >> 6;
    const int wt   = wid & 1;            // t half
    const int wk   = wid >> 1;           // k half
    const int l15  = lane & 15;
    const int quad = lane >> 4;

    const size_t bTt0 = (size_t)b * Tn + t0;

    int aoff[4], boff[4];
    #pragma unroll
    for (int i = 0; i < 4; ++i)
        aoff[i] = (wt * 64 + i * 16 + l15) * 32 + quad * 8;
    #pragma unroll
    for (int j = 0; j < 4; ++j)
        boff[j] = (wk * 64 + j * 16 + l15) * 32 + quad * 8;

    for (int kc = 0; kc < 2; ++kc) {
        const int k0 = kbase + kc * 128;

        f32x4 acc[4][4];
        #pragma unroll
        for (int i = 0; i < 4; ++i)
            #pragma unroll
            for (int j = 0; j < 4; ++j) acc[i][j] = (f32x4){0.f, 0.f, 0.f, 0.f};

        for (int dstep = 0; dstep < 8; ++dstep) {
            const int d0 = dstep * 32;
            __syncthreads();   // previous stage readers done / red-LDS safe

            #pragma unroll
            for (int r = 0; r < 2; ++r) {
                const int cb = (r * 4 + wid) << 6;     // wave-uniform chunk base
                const int c  = cb + lane;              // 0..511
                const int row = c >> 2;
                const int doff = d0 + (c & 3) * 8;
                const size_t ao = (bTt0 + row) * Dn + doff;
                const size_t bo = ((size_t)(k0 + row)) * Dn + doff;
                const int lb = cb * 8;                 // shorts
                GLOAD_LDS16(xh + ao, AhS + lb);
                GLOAD_LDS16(eh + bo, BhS + lb);
                GLOAD_LDS16(em + bo, BmS + lb);
            }
            __syncthreads();   // barrier drains vmcnt

            bf16x8 ah[4];
            #pragma unroll
            for (int i = 0; i < 4; ++i) ah[i] = *(const bf16x8*)(AhS + aoff[i]);
            #pragma unroll
            for (int j = 0; j < 4; ++j) {
                const bf16x8 bh = *(const bf16x8*)(BhS + boff[j]);
                const bf16x8 bm = *(const bf16x8*)(BmS + boff[j]);
                #pragma unroll
                for (int i = 0; i < 4; ++i) {
                    acc[i][j] = __builtin_amdgcn_mfma_f32_16x16x32_bf16(ah[i], bh, acc[i][j], 0, 0, 0);
                    acc[i][j] = __builtin_amdgcn_mfma_f32_16x16x32_bf16(ah[i], bm, acc[i][j], 0, 0, 0);
                }
            }
        }

        // ---- per-kc epilogue: bias, per-lane top-2 over j, butterfly over l15
        float bb[8]; int kv[4];
        #pragma unroll
        for (int j = 0; j < 4; ++j) {
            kv[j] = k0 + wk * 64 + j * 16 + l15;
            bb[j] = bias[kv[j]];
        }
        float s1[16], s2[16]; int k1[16];
        #pragma unroll
        for (int i = 0; i < 4; ++i) {
            #pragma unroll
            for (int r = 0; r < 4; ++r) {
                const int rr = i * 4 + r;
                s1[rr] = -INFINITY; s2[rr] = -INFINITY; k1[rr] = 0;
                #pragma unroll
                for (int j = 0; j < 4; ++j) {          // kv ascending in j
                    const float s = acc[i][j][r] - bb[j];
                    if (s > s1[rr]) { s2[rr] = s1[rr]; s1[rr] = s; k1[rr] = kv[j]; }
                    else if (s > s2[rr]) s2[rr] = s;
                }
            }
        }
        #pragma unroll
        for (int m = 1; m <= 8; m <<= 1) {
            #pragma unroll
            for (int rr = 0; rr < 16; ++rr) {
                const float os1 = __shfl_xor(s1[rr], m);
                const float os2 = __shfl_xor(s2[rr], m);
                const int   ok1 = __shfl_xor(k1[rr], m);
                const bool take = (os1 > s1[rr]) || (os1 == s1[rr] && ok1 < k1[rr]);
                const float ns2 = take ? fmaxf(s1[rr], os2) : fmaxf(s2[rr], os1);
                if (take) { s1[rr] = os1; k1[rr] = ok1; }
                s2[rr] = ns2;
            }
        }
        if (l15 == 0) {
            #pragma unroll
            for (int i = 0; i < 4; ++i)
                #pragma unroll
                for (int r = 0; r < 4; ++r) {
                    const int rr = i * 4 + r;
                    const int tl = wt * 64 + i * 16 + quad * 4 + r;
                    rS1[wk][tl] = s1[rr];
                    rS2[wk][tl] = s2[rr];
                    rKx[wk][tl] = k1[rr];
                }
        }
        __syncthreads();
        if (tid < 128) {
            const float a1 = rS1[0][tid], b1 = rS1[1][tid];
            float g1, g2; int kk;
            if (b1 > a1) { g1 = b1; kk = rKx[1][tid]; g2 = fmaxf(a1, rS2[1][tid]); }
            else         { g1 = a1; kk = rKx[0][tid]; g2 = fmaxf(b1, rS2[0][tid]); }
            uint2 e;
            e.x = __float_as_uint(g1);
            e.y = ((unsigned)bf16_up(g2) << 16) | (unsigned)kk;
            rec[(bTt0 + tid) * 16 + ks * 2 + kc] = e;
        }
        // next-kc loop-top __syncthreads covers red-LDS / staging reuse
    }
}

// ---------------------------------------------------------------------------
// Kernel 4: merge 16 packed records per point; codes + rescue list.
// g2 upper-bounded (bf16-up + partition seconds) -> conservative gap.
// ---------------------------------------------------------------------------
__global__ __launch_bounds__(256) void merge_kernel(
    const uint2* __restrict__ rec, int* __restrict__ codes_i,
    float* __restrict__ codes_f, int* __restrict__ list, int* __restrict__ counter)
{
    const int p = blockIdx.x * 256 + threadIdx.x;
    const uint2* r = rec + ((size_t)p << 4);
    uint2 e = r[0];
    float g1 = __uint_as_float(e.x);
    float g2 = __uint_as_float(e.y & 0xffff0000u);
    int kk = (int)(e.y & 0xffffu);
    #pragma unroll
    for (int s = 1; s < 16; ++s) {                    // slots ascending in k
        e = r[s];
        const float s1 = __uint_as_float(e.x);
        const float s2 = __uint_as_float(e.y & 0xffff0000u);
        if (s1 > g1) { g2 = fmaxf(g1, s2); g1 = s1; kk = (int)(e.y & 0xffffu); }
        else         { g2 = fmaxf(g2, fmaxf(s1, s2) < g1 ? fmaxf(s1, s2) : s1); }
    }
    codes_i[p] = kk;
    codes_f[p] = (float)kk;
    if (g1 - g2 < TAU) {
        const int idx = atomicAdd(counter, 1);
        list[idx] = p;
    }
}

// ---------------------------------------------------------------------------
// Kernel 5: exact fp32 rescore, one block per uncertain point.
// ---------------------------------------------------------------------------
__global__ __launch_bounds__(256) void rescue_kernel(
    const float* __restrict__ x, const float* __restrict__ emb,
    const float* __restrict__ bias, const int* __restrict__ list,
    const int* __restrict__ counter, int* __restrict__ codes_i,
    float* __restrict__ codes_f)
{
    __shared__ float xv[256];
    __shared__ float rs[4];
    __shared__ int   rk[4];
    const int tid = threadIdx.x, lane = tid & 63, wid = tid >> 6;
    const int count = *counter;
    for (int idx = blockIdx.x; idx < count; idx += gridDim.x) {
        __syncthreads();
        const int p = list[idx];
        const int bb = p >> 12, t = p & 4095;
        xv[tid] = x[((size_t)bb * Dn + tid) * Tn + t];
        __syncthreads();

        float acc[8];
        #pragma unroll
        for (int s = 0; s < 8; ++s) acc[s] = 0.f;
        const float4* e0 = (const float4*)emb + (size_t)tid * 64;
        for (int dc = 0; dc < 64; ++dc) {
            const float4 xw = *(const float4*)&xv[dc << 2];
            #pragma unroll
            for (int s = 0; s < 8; ++s) {
                const float4 e4 = e0[(size_t)s * 16384 + dc];
                acc[s] += e4.x * xw.x + e4.y * xw.y + e4.z * xw.z + e4.w * xw.w;
            }
        }
        float bs = -INFINITY; int bk = 0;
        #pragma unroll
        for (int s = 0; s < 8; ++s) {
            const int kk = tid + (s << 8);
            const float sc = acc[s] - bias[kk];
            if (sc > bs) { bs = sc; bk = kk; }
        }
        #pragma unroll
        for (int off = 1; off < 64; off <<= 1) {
            const float os = __shfl_xor(bs, off);
            const int   ok = __shfl_xor(bk, off);
            if (os > bs || (os == bs && ok < bk)) { bs = os; bk = ok; }
        }
        if (lane == 0) { rs[wid] = bs; rk[wid] = bk; }
        __syncthreads();
        if (tid == 0) {
            float fs = rs[0]; int fk = rk[0];
            #pragma unroll
            for (int w = 1; w < 4; ++w) {
                if (rs[w] > fs || (rs[w] == fs && rk[w] < fk)) { fs = rs[w]; fk = rk[w]; }
            }
            codes_i[p] = fk;
            codes_f[p] = (float)fk;
        }
    }
}

// ---------------------------------------------------------------------------
// Kernel 6: decode — decoded[b,d,t] = emb[codes[b,t]][d]
// ---------------------------------------------------------------------------
__global__ __launch_bounds__(256) void decode_kernel(
    const float* __restrict__ emb, const int* __restrict__ codes,
    float* __restrict__ out)
{
    const int b = blockIdx.y;
    const int t = blockIdx.x * 256 + threadIdx.x;
    const int c = codes[(size_t)b * Tn + t];
    const float4* e4 = (const float4*)(emb + (size_t)c * Dn);
    float* ob = out + (size_t)b * Dn * Tn + t;
    #pragma unroll 4
    for (int d4 = 0; d4 < 64; ++d4) {
        const float4 v = e4[d4];
        ob[(size_t)(d4 * 4 + 0) * Tn] = v.x;
        ob[(size_t)(d4 * 4 + 1) * Tn] = v.y;
        ob[(size_t)(d4 * 4 + 2) * Tn] = v.z;
        ob[(size_t)(d4 * 4 + 3) * Tn] = v.w;
    }
}

// ---------------------------------------------------------------------------
extern "C" void kernel_launch(void* const* d_in, const int* in_sizes, int n_in,
                              void* d_out, int out_size, void* d_ws, size_t ws_size,
                              hipStream_t stream) {
    const float* x     = (const float*)d_in[0];   // [B, D, T]
    const float* es    = (const float*)d_in[1];   // [K, D]
    const float* usage = (const float*)d_in[2];   // [K]

    // ws layout (byte offsets, 16-aligned) — ~12.8 MiB, within proven budget
    char* ws = (char*)d_ws;
    float*    emb     = (float*)(ws + 0);                // 2 MiB
    float*    bias    = (float*)(ws + 2097152);          // 8 KB
    ushort_t* eh      = (ushort_t*)(ws + 2105344);       // 1 MiB
    ushort_t* em      = (ushort_t*)(ws + 3153920);       // 1 MiB
    uint2*    rec     = (uint2*)(ws + 4202496);          // 8 MiB (65536*16*8B)
    int*      codes_i = (int*)(ws + 12591104);           // 256 KB
    int*      list    = (int*)(ws + 12853248);           // 256 KB
    int*      counter = (int*)(ws + 13115392);           // 4 B

    float* codes_f = (float*)d_out;                      // [B*T]
    float* decoded = (float*)d_out + (size_t)Bn * Tn;    // [B*D*T], 64 MiB

    // xh lives in the decoded region (32 of 64 MiB); decode overwrites last.
    ushort_t* xh = (ushort_t*)decoded;                   // 32 MiB

    prep_kernel<<<Kn, 256, 0, stream>>>(es, usage, emb, eh, em, bias, counter);

    dim3 gx(Tn / 16, Bn);
    xsplit_kernel<<<gx, 256, 0, stream>>>(x, xh);

    gemm_argmax<<<4096, 256, 0, stream>>>(xh, eh, em, bias, rec);

    merge_kernel<<<(Bn * Tn) / 256, 256, 0, stream>>>(rec, codes_i, codes_f, list, counter);

    rescue_kernel<<<2048, 256, 0, stream>>>(x, emb, bias, list, counter, codes_i, codes_f);

    dim3 g6(Tn / 256, Bn);
    decode_kernel<<<g6, 256, 0, stream>>>(emb, codes_i, decoded);
}

// Round 5
// 556.823 us; speedup vs baseline: 3.2866x; 3.2866x over previous
//
#include <hip/hip_runtime.h>
#include <hip/hip_fp16.h>
#include <cmath>

#define EPS 1e-5f
#define TAU 0.25f
#define RP  8

// Problem constants (fixed instance)
#define Bn 16
#define Dn 256
#define Tn 4096
#define Kn 2048

typedef unsigned short ushort_t;
typedef __attribute__((ext_vector_type(8))) short bf16x8;
typedef __attribute__((ext_vector_type(4))) float f32x4;

__device__ __forceinline__ unsigned short f2bf(float v, float& back) {
    union { float f; unsigned u; } a; a.f = v;
    unsigned r = a.u + 0x7fffu + ((a.u >> 16) & 1u);   // RNE
    unsigned short h = (unsigned short)(r >> 16);
    union { float f; unsigned u; } b; b.u = ((unsigned)h) << 16;
    back = b.f;
    return h;
}

// fp16 rounded UP in value (result >= v). ulp <= 0.125 for |v| < 256.
__device__ __forceinline__ unsigned short f16_up(float v) {
    const __half h = __float2half_rn(v);
    const float back = __half2float(h);
    unsigned short u = __half_as_ushort(h);
    if (back < v) u = (u & 0x8000u) ? (u - 1) : (u + 1);
    return u;
}

#define GLOAD_LDS16(gp, lp) __builtin_amdgcn_global_load_lds( \
    (const __attribute__((address_space(1))) unsigned int*)(gp), \
    (__attribute__((address_space(3))) unsigned int*)(lp), 16, 0, 0)

// ---------------------------------------------------------------------------
// Kernel 1: prep — emb = es/max(usage,eps); bf16 hi/mid planes; bias=0.5|e|^2;
// embT4 = f4-transposed codebook [64 dc][2048 k] for coalesced rescue reads.
// ---------------------------------------------------------------------------
__global__ __launch_bounds__(256) void prep_kernel(
    const float* __restrict__ es, const float* __restrict__ usage,
    float* __restrict__ emb, ushort_t* __restrict__ eh,
    ushort_t* __restrict__ em, float* __restrict__ bias,
    float4* __restrict__ embT4, int* __restrict__ counter)
{
    __shared__ float sh[256];
    __shared__ float wsum[4];
    const int k = blockIdx.x;
    const int d = threadIdx.x;
    const float inv = 1.0f / fmaxf(usage[k], EPS);
    const float v = es[(size_t)k * Dn + d] * inv;
    emb[(size_t)k * Dn + d] = v;
    float hb, dummy;
    const unsigned short h = f2bf(v, hb);
    eh[(size_t)k * Dn + d] = h;
    em[(size_t)k * Dn + d] = f2bf(v - hb, dummy);
    sh[d] = v;
    float sq = v * v;
    #pragma unroll
    for (int off = 32; off > 0; off >>= 1) sq += __shfl_down(sq, off, 64);
    const int lane = d & 63, wv = d >> 6;
    if (lane == 0) wsum[wv] = sq;
    __syncthreads();
    if (d < 64)
        embT4[(size_t)d * Kn + k] = make_float4(sh[4*d], sh[4*d+1], sh[4*d+2], sh[4*d+3]);
    if (d == 0) {
        bias[k] = 0.5f * (wsum[0] + wsum[1] + wsum[2] + wsum[3]);
        if (k == 0) *counter = 0;
    }
}

// ---------------------------------------------------------------------------
// Kernel 2: xsplit — x[b][d][t] fp32 -> xh[b][t][d] bf16 (hi plane only).
// ---------------------------------------------------------------------------
__global__ __launch_bounds__(256) void xsplit_kernel(
    const float* __restrict__ x, ushort_t* __restrict__ xh)
{
    __shared__ float tile[256 * 17];
    const int t0 = blockIdx.x * 16;
    const int b  = blockIdx.y;
    const int tid = threadIdx.x;
    {
        const float* src = x + ((size_t)(b * Dn + tid)) * Tn + t0;
        float* row = &tile[tid * 17];
        #pragma unroll
        for (int q = 0; q < 4; ++q) {
            const float4 a = *(const float4*)(src + q * 4);
            row[q * 4 + 0] = a.x; row[q * 4 + 1] = a.y;
            row[q * 4 + 2] = a.z; row[q * 4 + 3] = a.w;
        }
    }
    __syncthreads();
    {
        const int tq = tid >> 4, dq = tid & 15;
        #pragma unroll
        for (int u = 0; u < 2; ++u) {
            const int c = dq + u * 16;
            unsigned wh[4];
            #pragma unroll
            for (int i = 0; i < 4; ++i) {
                const float a = tile[(c * 8 + 2 * i) * 17 + tq];
                const float g = tile[(c * 8 + 2 * i + 1) * 17 + tq];
                float hb, dummy;
                const unsigned short h0 = f2bf(a, hb);
                const unsigned short h1 = f2bf(g, dummy);
                wh[i] = (unsigned)h0 | ((unsigned)h1 << 16);
            }
            const size_t o = ((size_t)(b * Tn + t0 + tq)) * Dn + c * 8;
            *(uint4*)(xh + o) = make_uint4(wh[0], wh[1], wh[2], wh[3]);
        }
    }
}

// ---------------------------------------------------------------------------
// Kernel 3: 2-product MFMA GEMM + top-2 argmax.  s ~= xh.(eh+em).
// Block 256thr/4 waves (2x2), wave-tile 64t x 64k, KSPLIT=8 (256 k/block,
// 2 kc passes merged in-register), BK=32. One 8 B record per (point, ks):
// slot-major rec[ks][p] = (s1 fp32, s2 fp16-up, k).
// ---------------------------------------------------------------------------
__global__ __launch_bounds__(256, 3) void gemm_argmax(
    const ushort_t* __restrict__ xh, const ushort_t* __restrict__ eh,
    const ushort_t* __restrict__ em, const float* __restrict__ bias,
    uint2* __restrict__ rec)
{
    __shared__ ushort_t AhS[128 * 32];   // 8 KB  [t][d32]
    __shared__ ushort_t BhS[128 * 32];   // 8 KB  [k][d32]
    __shared__ ushort_t BmS[128 * 32];   // 8 KB
    __shared__ float rS1[2][128];
    __shared__ float rS2[2][128];
    __shared__ int   rKx[2][128];

    const int bid   = blockIdx.x;
    const int xcd   = bid & 7;
    const int ks    = (bid >> 3) & 7;
    const int tilid = bid >> 6;
    const int gtile = tilid * 8 + xcd;   // ks-siblings of one (b,tt) share an XCD
    const int b     = gtile >> 5;
    const int tt    = gtile & 31;
    const int t0    = tt << 7;
    const int kbase = ks << 8;

    const int tid  = threadIdx.x;
    const int lane = tid & 63;
    const int wid  = tid >> 6;
    const int wt   = wid & 1;            // t half
    const int wk   = wid >> 1;           // k half
    const int l15  = lane & 15;
    const int quad = lane >> 4;

    const size_t bTt0 = (size_t)b * Tn + t0;

    int aoff[4], boff[4];
    #pragma unroll
    for (int i = 0; i < 4; ++i)
        aoff[i] = (wt * 64 + i * 16 + l15) * 32 + quad * 8;
    #pragma unroll
    for (int j = 0; j < 4; ++j)
        boff[j] = (wk * 64 + j * 16 + l15) * 32 + quad * 8;

    float g1r = 0.f, g2r = 0.f; int kkr = 0;   // live in tid<128

    for (int kc = 0; kc < 2; ++kc) {
        const int k0 = kbase + kc * 128;

        f32x4 acc[4][4];
        #pragma unroll
        for (int i = 0; i < 4; ++i)
            #pragma unroll
            for (int j = 0; j < 4; ++j) acc[i][j] = (f32x4){0.f, 0.f, 0.f, 0.f};

        for (int dstep = 0; dstep < 8; ++dstep) {
            const int d0 = dstep * 32;
            __syncthreads();   // previous stage readers done / red-LDS safe

            #pragma unroll
            for (int r = 0; r < 2; ++r) {
                const int cb = (r * 4 + wid) << 6;     // wave-uniform chunk base
                const int c  = cb + lane;              // 0..511
                const int row = c >> 2;
                const int doff = d0 + (c & 3) * 8;
                const size_t ao = (bTt0 + row) * Dn + doff;
                const size_t bo = ((size_t)(k0 + row)) * Dn + doff;
                const int lb = cb * 8;                 // shorts
                GLOAD_LDS16(xh + ao, AhS + lb);
                GLOAD_LDS16(eh + bo, BhS + lb);
                GLOAD_LDS16(em + bo, BmS + lb);
            }
            __syncthreads();   // barrier drains vmcnt

            bf16x8 ah[4];
            #pragma unroll
            for (int i = 0; i < 4; ++i) ah[i] = *(const bf16x8*)(AhS + aoff[i]);
            #pragma unroll
            for (int j = 0; j < 4; ++j) {
                const bf16x8 bh = *(const bf16x8*)(BhS + boff[j]);
                const bf16x8 bm = *(const bf16x8*)(BmS + boff[j]);
                #pragma unroll
                for (int i = 0; i < 4; ++i) {
                    acc[i][j] = __builtin_amdgcn_mfma_f32_16x16x32_bf16(ah[i], bh, acc[i][j], 0, 0, 0);
                    acc[i][j] = __builtin_amdgcn_mfma_f32_16x16x32_bf16(ah[i], bm, acc[i][j], 0, 0, 0);
                }
            }
        }

        // ---- per-kc epilogue: bias, per-lane top-2 over j, butterfly over l15
        float bb[4]; int kv[4];
        #pragma unroll
        for (int j = 0; j < 4; ++j) {
            kv[j] = k0 + wk * 64 + j * 16 + l15;
            bb[j] = bias[kv[j]];
        }
        float s1[16], s2[16]; int k1[16];
        #pragma unroll
        for (int i = 0; i < 4; ++i) {
            #pragma unroll
            for (int r = 0; r < 4; ++r) {
                const int rr = i * 4 + r;
                s1[rr] = -INFINITY; s2[rr] = -INFINITY; k1[rr] = 0;
                #pragma unroll
                for (int j = 0; j < 4; ++j) {          // kv ascending in j
                    const float s = acc[i][j][r] - bb[j];
                    if (s > s1[rr]) { s2[rr] = s1[rr]; s1[rr] = s; k1[rr] = kv[j]; }
                    else if (s > s2[rr]) s2[rr] = s;
                }
            }
        }
        #pragma unroll
        for (int m = 1; m <= 8; m <<= 1) {
            #pragma unroll
            for (int rr = 0; rr < 16; ++rr) {
                const float os1 = __shfl_xor(s1[rr], m);
                const float os2 = __shfl_xor(s2[rr], m);
                const int   ok1 = __shfl_xor(k1[rr], m);
                const bool take = (os1 > s1[rr]) || (os1 == s1[rr] && ok1 < k1[rr]);
                const float ns2 = take ? fmaxf(s1[rr], os2) : fmaxf(s2[rr], os1);
                if (take) { s1[rr] = os1; k1[rr] = ok1; }
                s2[rr] = ns2;
            }
        }
        if (l15 == 0) {
            #pragma unroll
            for (int i = 0; i < 4; ++i)
                #pragma unroll
                for (int r = 0; r < 4; ++r) {
                    const int rr = i * 4 + r;
                    const int tl = wt * 64 + i * 16 + quad * 4 + r;
                    rS1[wk][tl] = s1[rr];
                    rS2[wk][tl] = s2[rr];
                    rKx[wk][tl] = k1[rr];
                }
        }
        __syncthreads();
        if (tid < 128) {
            const float a1 = rS1[0][tid], b1 = rS1[1][tid];
            float m1, m2; int mk;
            if (b1 > a1) { m1 = b1; mk = rKx[1][tid]; m2 = fmaxf(a1, rS2[1][tid]); }
            else         { m1 = a1; mk = rKx[0][tid]; m2 = fmaxf(b1, rS2[0][tid]); }
            if (kc == 0) { g1r = m1; g2r = m2; kkr = mk; }
            else {
                if (m1 > g1r) { g2r = fmaxf(g1r, fmaxf(g2r, m2)); g1r = m1; kkr = mk; }
                else          { g2r = fmaxf(g2r, m1); }
            }
        }
    }

    if (tid < 128) {
        uint2 e;
        e.x = __float_as_uint(g1r);
        e.y = ((unsigned)f16_up(g2r) << 16) | (unsigned)kkr;
        rec[(size_t)ks * (Bn * Tn) + bTt0 + tid] = e;   // slot-major, coalesced
    }
}

// ---------------------------------------------------------------------------
// Kernel 4: merge 8 slot-major records per point; codes + rescue list.
// Non-winner slots contribute exact fp32 s1; winner's s2 is fp16-up bound.
// ---------------------------------------------------------------------------
__global__ __launch_bounds__(256) void merge_kernel(
    const uint2* __restrict__ rec, int* __restrict__ codes_i,
    float* __restrict__ codes_f, int* __restrict__ list, int* __restrict__ counter)
{
    const int p = blockIdx.x * 256 + threadIdx.x;
    uint2 e = rec[p];
    float g1 = __uint_as_float(e.x);
    float g2 = __half2float(__ushort_as_half((unsigned short)(e.y >> 16)));
    int kk = (int)(e.y & 0xffffu);
    #pragma unroll
    for (int s = 1; s < 8; ++s) {                     // slots ascending in k
        e = rec[(size_t)s * (Bn * Tn) + p];
        const float s1 = __uint_as_float(e.x);
        if (s1 > g1) {
            const float s2u = __half2float(__ushort_as_half((unsigned short)(e.y >> 16)));
            g2 = fmaxf(fmaxf(g2, g1), s2u);
            g1 = s1;
            kk = (int)(e.y & 0xffffu);
        } else {
            g2 = fmaxf(g2, s1);
        }
    }
    codes_i[p] = kk;
    codes_f[p] = (float)kk;
    if (g1 - g2 < TAU) {
        const int idx = atomicAdd(counter, 1);
        list[idx] = p;
    }
}

// ---------------------------------------------------------------------------
// Kernel 5: exact fp32 rescore, RP=8 points per block pass.
// Coalesced codebook reads via embT4 [dc][k]; 256 FMA/thread/iter hides
// latency; per-point cost ~2 µs (vs 45 µs in the R4 one-point version).
// ---------------------------------------------------------------------------
__global__ __launch_bounds__(256) void rescue_kernel(
    const float* __restrict__ x, const float4* __restrict__ embT4,
    const float* __restrict__ bias, const int* __restrict__ list,
    const int* __restrict__ counter, int* __restrict__ codes_i,
    float* __restrict__ codes_f)
{
    __shared__ float xv[RP][256];
    __shared__ int plist[RP];
    __shared__ float rs[RP][4];
    __shared__ int   rk[RP][4];
    const int tid = threadIdx.x, lane = tid & 63, wid = tid >> 6;
    const int count = *counter;
    for (int base = blockIdx.x * RP; base < count; base += gridDim.x * RP) {
        const int npts = min(RP, count - base);
        __syncthreads();   // protect LDS from previous iteration's readers
        if (tid < npts) plist[tid] = list[base + tid];
        __syncthreads();
        for (int pi = 0; pi < npts; ++pi) {
            const int p = plist[pi];
            xv[pi][tid] = x[((size_t)((p >> 12) * Dn + tid)) * Tn + (p & 4095)];
        }
        for (int pi = npts; pi < RP; ++pi) xv[pi][tid] = 0.f;
        __syncthreads();

        float acc[8][RP];
        #pragma unroll
        for (int s = 0; s < 8; ++s)
            #pragma unroll
            for (int pi = 0; pi < RP; ++pi) acc[s][pi] = 0.f;

        for (int dc = 0; dc < 64; ++dc) {
            float4 ev[8];
            #pragma unroll
            for (int s = 0; s < 8; ++s)
                ev[s] = embT4[(size_t)dc * Kn + tid + (s << 8)];   // coalesced
            #pragma unroll
            for (int pi = 0; pi < RP; ++pi) {
                const float4 xw = *(const float4*)&xv[pi][dc << 2];
                #pragma unroll
                for (int s = 0; s < 8; ++s)
                    acc[s][pi] += ev[s].x * xw.x + ev[s].y * xw.y
                                + ev[s].z * xw.z + ev[s].w * xw.w;
            }
        }

        float bs[RP]; int bk[RP];
        #pragma unroll
        for (int pi = 0; pi < RP; ++pi) { bs[pi] = -INFINITY; bk[pi] = 0; }
        #pragma unroll
        for (int s = 0; s < 8; ++s) {
            const int kk = tid + (s << 8);           // ascending per thread
            const float bv = bias[kk];
            #pragma unroll
            for (int pi = 0; pi < RP; ++pi) {
                const float sc = acc[s][pi] - bv;
                if (sc > bs[pi]) { bs[pi] = sc; bk[pi] = kk; }
            }
        }
        #pragma unroll
        for (int off = 1; off < 64; off <<= 1) {
            #pragma unroll
            for (int pi = 0; pi < RP; ++pi) {
                const float os = __shfl_xor(bs[pi], off);
                const int   ok = __shfl_xor(bk[pi], off);
                if (os > bs[pi] || (os == bs[pi] && ok < bk[pi])) { bs[pi] = os; bk[pi] = ok; }
            }
        }
        if (lane == 0) {
            #pragma unroll
            for (int pi = 0; pi < RP; ++pi) { rs[pi][wid] = bs[pi]; rk[pi][wid] = bk[pi]; }
        }
        __syncthreads();
        if (tid < npts) {
            float fs = rs[tid][0]; int fk = rk[tid][0];
            #pragma unroll
            for (int w = 1; w < 4; ++w) {
                if (rs[tid][w] > fs || (rs[tid][w] == fs && rk[tid][w] < fk)) {
                    fs = rs[tid][w]; fk = rk[tid][w];
                }
            }
            const int p = plist[tid];
            codes_i[p] = fk;
            codes_f[p] = (float)fk;
        }
    }
}

// ---------------------------------------------------------------------------
// Kernel 6: decode — decoded[b,d,t] = emb[codes[b,t]][d]
// ---------------------------------------------------------------------------
__global__ __launch_bounds__(256) void decode_kernel(
    const float* __restrict__ emb, const int* __restrict__ codes,
    float* __restrict__ out)
{
    const int b = blockIdx.y;
    const int t = blockIdx.x * 256 + threadIdx.x;
    const int c = codes[(size_t)b * Tn + t];
    const float4* e4 = (const float4*)(emb + (size_t)c * Dn);
    float* ob = out + (size_t)b * Dn * Tn + t;
    #pragma unroll 4
    for (int d4 = 0; d4 < 64; ++d4) {
        const float4 v = e4[d4];
        ob[(size_t)(d4 * 4 + 0) * Tn] = v.x;
        ob[(size_t)(d4 * 4 + 1) * Tn] = v.y;
        ob[(size_t)(d4 * 4 + 2) * Tn] = v.z;
        ob[(size_t)(d4 * 4 + 3) * Tn] = v.w;
    }
}

// ---------------------------------------------------------------------------
extern "C" void kernel_launch(void* const* d_in, const int* in_sizes, int n_in,
                              void* d_out, int out_size, void* d_ws, size_t ws_size,
                              hipStream_t stream) {
    const float* x     = (const float*)d_in[0];   // [B, D, T]
    const float* es    = (const float*)d_in[1];   // [K, D]
    const float* usage = (const float*)d_in[2];   // [K]

    // ws layout (byte offsets, 16-aligned) — ~10.5 MiB (< proven 13.1 MiB)
    char* ws = (char*)d_ws;
    float*    emb     = (float*)(ws + 0);                // 2 MiB
    float*    bias    = (float*)(ws + 2097152);          // 8 KB
    ushort_t* eh      = (ushort_t*)(ws + 2105344);       // 1 MiB
    ushort_t* em      = (ushort_t*)(ws + 3153920);       // 1 MiB
    float4*   embT4   = (float4*)(ws + 4202496);         // 2 MiB
    uint2*    rec     = (uint2*)(ws + 6299648);          // 4 MiB (8 x 65536 x 8B)
    int*      codes_i = (int*)(ws + 10493952);           // 256 KB
    int*      list    = (int*)(ws + 10756096);           // 256 KB
    int*      counter = (int*)(ws + 11018240);           // 4 B

    float* codes_f = (float*)d_out;                      // [B*T]
    float* decoded = (float*)d_out + (size_t)Bn * Tn;    // [B*D*T], 64 MiB

    // xh lives in the decoded region (32 of 64 MiB); decode overwrites last.
    ushort_t* xh = (ushort_t*)decoded;                   // 32 MiB

    prep_kernel<<<Kn, 256, 0, stream>>>(es, usage, emb, eh, em, bias, embT4, counter);

    dim3 gx(Tn / 16, Bn);
    xsplit_kernel<<<gx, 256, 0, stream>>>(x, xh);

    gemm_argmax<<<4096, 256, 0, stream>>>(xh, eh, em, bias, rec);

    merge_kernel<<<(Bn * Tn) / 256, 256, 0, stream>>>(rec, codes_i, codes_f, list, counter);

    rescue_kernel<<<1024, 256, 0, stream>>>(x, embT4, bias, list, counter, codes_i, codes_f);

    dim3 g6(Tn / 256, Bn);
    decode_kernel<<<g6, 256, 0, stream>>>(emb, codes_i, decoded);
}

// Round 6
// 474.460 us; speedup vs baseline: 3.8572x; 1.1736x over previous
//
#include <hip/hip_runtime.h>
#include <hip/hip_fp16.h>
#include <cmath>

#define EPS 1e-5f
#define TAU 0.25f
#define RP  8

// Problem constants (fixed instance)
#define Bn 16
#define Dn 256
#define Tn 4096
#define Kn 2048

typedef unsigned short ushort_t;
typedef __attribute__((ext_vector_type(8))) short bf16x8;
typedef __attribute__((ext_vector_type(4))) float f32x4;

__device__ __forceinline__ unsigned short f2bf(float v, float& back) {
    union { float f; unsigned u; } a; a.f = v;
    unsigned r = a.u + 0x7fffu + ((a.u >> 16) & 1u);   // RNE
    unsigned short h = (unsigned short)(r >> 16);
    union { float f; unsigned u; } b; b.u = ((unsigned)h) << 16;
    back = b.f;
    return h;
}

// fp16 rounded UP in value (result >= v). ulp <= 0.125 for |v| < 256.
__device__ __forceinline__ unsigned short f16_up(float v) {
    const __half h = __float2half_rn(v);
    const float back = __half2float(h);
    unsigned short u = __half_as_ushort(h);
    if (back < v) u = (u & 0x8000u) ? (u - 1) : (u + 1);
    return u;
}

#define GLOAD_LDS16(gp, lp) __builtin_amdgcn_global_load_lds( \
    (const __attribute__((address_space(1))) unsigned int*)(gp), \
    (__attribute__((address_space(3))) unsigned int*)(lp), 16, 0, 0)

// ---------------------------------------------------------------------------
// Kernel 1: prep — emb = es/max(usage,eps); bf16 hi/mid planes; bias=0.5|e|^2;
// embT4 = f4-transposed codebook [64 dc][2048 k] for coalesced rescue reads.
// ---------------------------------------------------------------------------
__global__ __launch_bounds__(256) void prep_kernel(
    const float* __restrict__ es, const float* __restrict__ usage,
    float* __restrict__ emb, ushort_t* __restrict__ eh,
    ushort_t* __restrict__ em, float* __restrict__ bias,
    float4* __restrict__ embT4, int* __restrict__ counter)
{
    __shared__ float sh[256];
    __shared__ float wsum[4];
    const int k = blockIdx.x;
    const int d = threadIdx.x;
    const float inv = 1.0f / fmaxf(usage[k], EPS);
    const float v = es[(size_t)k * Dn + d] * inv;
    emb[(size_t)k * Dn + d] = v;
    float hb, dummy;
    const unsigned short h = f2bf(v, hb);
    eh[(size_t)k * Dn + d] = h;
    em[(size_t)k * Dn + d] = f2bf(v - hb, dummy);
    sh[d] = v;
    float sq = v * v;
    #pragma unroll
    for (int off = 32; off > 0; off >>= 1) sq += __shfl_down(sq, off, 64);
    const int lane = d & 63, wv = d >> 6;
    if (lane == 0) wsum[wv] = sq;
    __syncthreads();
    if (d < 64)
        embT4[(size_t)d * Kn + k] = make_float4(sh[4*d], sh[4*d+1], sh[4*d+2], sh[4*d+3]);
    if (d == 0) {
        bias[k] = 0.5f * (wsum[0] + wsum[1] + wsum[2] + wsum[3]);
        if (k == 0) *counter = 0;
    }
}

// ---------------------------------------------------------------------------
// Kernel 2: xsplit — x[b][d][t] fp32 -> xh[b][t][d] bf16 (hi plane only).
// ---------------------------------------------------------------------------
__global__ __launch_bounds__(256) void xsplit_kernel(
    const float* __restrict__ x, ushort_t* __restrict__ xh)
{
    __shared__ float tile[256 * 17];
    const int t0 = blockIdx.x * 16;
    const int b  = blockIdx.y;
    const int tid = threadIdx.x;
    {
        const float* src = x + ((size_t)(b * Dn + tid)) * Tn + t0;
        float* row = &tile[tid * 17];
        #pragma unroll
        for (int q = 0; q < 4; ++q) {
            const float4 a = *(const float4*)(src + q * 4);
            row[q * 4 + 0] = a.x; row[q * 4 + 1] = a.y;
            row[q * 4 + 2] = a.z; row[q * 4 + 3] = a.w;
        }
    }
    __syncthreads();
    {
        const int tq = tid >> 4, dq = tid & 15;
        #pragma unroll
        for (int u = 0; u < 2; ++u) {
            const int c = dq + u * 16;
            unsigned wh[4];
            #pragma unroll
            for (int i = 0; i < 4; ++i) {
                const float a = tile[(c * 8 + 2 * i) * 17 + tq];
                const float g = tile[(c * 8 + 2 * i + 1) * 17 + tq];
                float hb, dummy;
                const unsigned short h0 = f2bf(a, hb);
                const unsigned short h1 = f2bf(g, dummy);
                wh[i] = (unsigned)h0 | ((unsigned)h1 << 16);
            }
            const size_t o = ((size_t)(b * Tn + t0 + tq)) * Dn + c * 8;
            *(uint4*)(xh + o) = make_uint4(wh[0], wh[1], wh[2], wh[3]);
        }
    }
}

// ---------------------------------------------------------------------------
// Kernel 3: 2-product MFMA GEMM + top-2 argmax.  s ~= xh.(eh+em).
// Block 256thr/4 waves (2x2), wave-tile 64t x 64k, KSPLIT=8 (256 k/block,
// 2 kc passes merged in-register), BK=32. Epilogue processes ONE i-tile at a
// time (4 rows) to keep live registers low — R5's 16-row arrays caused
// scratch spills (201 MB WRITE_SIZE). One 8 B record per (point, ks).
// ---------------------------------------------------------------------------
__global__ __launch_bounds__(256, 3) void gemm_argmax(
    const ushort_t* __restrict__ xh, const ushort_t* __restrict__ eh,
    const ushort_t* __restrict__ em, const float* __restrict__ bias,
    uint2* __restrict__ rec)
{
    __shared__ ushort_t AhS[128 * 32];   // 8 KB  [t][d32]
    __shared__ ushort_t BhS[128 * 32];   // 8 KB  [k][d32]
    __shared__ ushort_t BmS[128 * 32];   // 8 KB
    __shared__ float rS1[2][128];
    __shared__ float rS2[2][128];
    __shared__ int   rKx[2][128];

    const int bid   = blockIdx.x;
    const int xcd   = bid & 7;
    const int ks    = (bid >> 3) & 7;
    const int tilid = bid >> 6;
    const int gtile = tilid * 8 + xcd;   // ks-siblings of one (b,tt) share an XCD
    const int b     = gtile >> 5;
    const int tt    = gtile & 31;
    const int t0    = tt << 7;
    const int kbase = ks << 8;

    const int tid  = threadIdx.x;
    const int lane = tid & 63;
    const int wid  = tid >> 6;
    const int wt   = wid & 1;            // t half
    const int wk   = wid >> 1;           // k half
    const int l15  = lane & 15;
    const int quad = lane >> 4;

    const size_t bTt0 = (size_t)b * Tn + t0;

    int aoff[4], boff[4];
    #pragma unroll
    for (int i = 0; i < 4; ++i)
        aoff[i] = (wt * 64 + i * 16 + l15) * 32 + quad * 8;
    #pragma unroll
    for (int j = 0; j < 4; ++j)
        boff[j] = (wk * 64 + j * 16 + l15) * 32 + quad * 8;

    float g1r = 0.f, g2r = 0.f; int kkr = 0;   // live in tid<128

    for (int kc = 0; kc < 2; ++kc) {
        const int k0 = kbase + kc * 128;

        f32x4 acc[4][4];
        #pragma unroll
        for (int i = 0; i < 4; ++i)
            #pragma unroll
            for (int j = 0; j < 4; ++j) acc[i][j] = (f32x4){0.f, 0.f, 0.f, 0.f};

        for (int dstep = 0; dstep < 8; ++dstep) {
            const int d0 = dstep * 32;
            __syncthreads();   // previous stage readers done / red-LDS safe

            #pragma unroll
            for (int r = 0; r < 2; ++r) {
                const int cb = (r * 4 + wid) << 6;     // wave-uniform chunk base
                const int c  = cb + lane;              // 0..511
                const int row = c >> 2;
                const int doff = d0 + (c & 3) * 8;
                const size_t ao = (bTt0 + row) * Dn + doff;
                const size_t bo = ((size_t)(k0 + row)) * Dn + doff;
                const int lb = cb * 8;                 // shorts
                GLOAD_LDS16(xh + ao, AhS + lb);
                GLOAD_LDS16(eh + bo, BhS + lb);
                GLOAD_LDS16(em + bo, BmS + lb);
            }
            __syncthreads();   // barrier drains vmcnt

            bf16x8 ah[4];
            #pragma unroll
            for (int i = 0; i < 4; ++i) ah[i] = *(const bf16x8*)(AhS + aoff[i]);
            #pragma unroll
            for (int j = 0; j < 4; ++j) {
                const bf16x8 bh = *(const bf16x8*)(BhS + boff[j]);
                const bf16x8 bm = *(const bf16x8*)(BmS + boff[j]);
                #pragma unroll
                for (int i = 0; i < 4; ++i) {
                    acc[i][j] = __builtin_amdgcn_mfma_f32_16x16x32_bf16(ah[i], bh, acc[i][j], 0, 0, 0);
                    acc[i][j] = __builtin_amdgcn_mfma_f32_16x16x32_bf16(ah[i], bm, acc[i][j], 0, 0, 0);
                }
            }
        }

        // ---- per-kc epilogue, ONE i-tile at a time (low register pressure) --
        float bb[4]; int kv[4];
        #pragma unroll
        for (int j = 0; j < 4; ++j) {
            kv[j] = k0 + wk * 64 + j * 16 + l15;
            bb[j] = bias[kv[j]];
        }
        #pragma unroll
        for (int i = 0; i < 4; ++i) {
            float s1l[4], s2l[4]; int k1l[4];
            #pragma unroll
            for (int r = 0; r < 4; ++r) {
                s1l[r] = -INFINITY; s2l[r] = -INFINITY; k1l[r] = 0;
                #pragma unroll
                for (int j = 0; j < 4; ++j) {          // kv ascending in j
                    const float s = acc[i][j][r] - bb[j];
                    if (s > s1l[r]) { s2l[r] = s1l[r]; s1l[r] = s; k1l[r] = kv[j]; }
                    else if (s > s2l[r]) s2l[r] = s;
                }
            }
            #pragma unroll
            for (int m = 1; m <= 8; m <<= 1) {
                #pragma unroll
                for (int r = 0; r < 4; ++r) {
                    const float os1 = __shfl_xor(s1l[r], m);
                    const float os2 = __shfl_xor(s2l[r], m);
                    const int   ok1 = __shfl_xor(k1l[r], m);
                    const bool take = (os1 > s1l[r]) || (os1 == s1l[r] && ok1 < k1l[r]);
                    const float ns2 = take ? fmaxf(s1l[r], os2) : fmaxf(s2l[r], os1);
                    if (take) { s1l[r] = os1; k1l[r] = ok1; }
                    s2l[r] = ns2;
                }
            }
            if (l15 == 0) {
                #pragma unroll
                for (int r = 0; r < 4; ++r) {
                    const int tl = wt * 64 + i * 16 + quad * 4 + r;
                    rS1[wk][tl] = s1l[r];
                    rS2[wk][tl] = s2l[r];
                    rKx[wk][tl] = k1l[r];
                }
            }
        }
        __syncthreads();
        if (tid < 128) {
            const float a1 = rS1[0][tid], b1 = rS1[1][tid];
            float m1, m2; int mk;
            if (b1 > a1) { m1 = b1; mk = rKx[1][tid]; m2 = fmaxf(a1, rS2[1][tid]); }
            else         { m1 = a1; mk = rKx[0][tid]; m2 = fmaxf(b1, rS2[0][tid]); }
            if (kc == 0) { g1r = m1; g2r = m2; kkr = mk; }
            else {
                if (m1 > g1r) { g2r = fmaxf(g1r, fmaxf(g2r, m2)); g1r = m1; kkr = mk; }
                else          { g2r = fmaxf(g2r, m1); }
            }
        }
    }

    if (tid < 128) {
        uint2 e;
        e.x = __float_as_uint(g1r);
        e.y = ((unsigned)f16_up(g2r) << 16) | (unsigned)kkr;
        rec[(size_t)ks * (Bn * Tn) + bTt0 + tid] = e;   // slot-major, coalesced
    }
}

// ---------------------------------------------------------------------------
// Kernel 4: merge 8 slot-major records per point; codes + rescue list.
// ---------------------------------------------------------------------------
__global__ __launch_bounds__(256) void merge_kernel(
    const uint2* __restrict__ rec, int* __restrict__ codes_i,
    float* __restrict__ codes_f, int* __restrict__ list, int* __restrict__ counter)
{
    const int p = blockIdx.x * 256 + threadIdx.x;
    uint2 e = rec[p];
    float g1 = __uint_as_float(e.x);
    float g2 = __half2float(__ushort_as_half((unsigned short)(e.y >> 16)));
    int kk = (int)(e.y & 0xffffu);
    #pragma unroll
    for (int s = 1; s < 8; ++s) {                     // slots ascending in k
        e = rec[(size_t)s * (Bn * Tn) + p];
        const float s1 = __uint_as_float(e.x);
        if (s1 > g1) {
            const float s2u = __half2float(__ushort_as_half((unsigned short)(e.y >> 16)));
            g2 = fmaxf(fmaxf(g2, g1), s2u);
            g1 = s1;
            kk = (int)(e.y & 0xffffu);
        } else {
            g2 = fmaxf(g2, s1);
        }
    }
    codes_i[p] = kk;
    codes_f[p] = (float)kk;
    if (g1 - g2 < TAU) {
        const int idx = atomicAdd(counter, 1);
        list[idx] = p;
    }
}

// ---------------------------------------------------------------------------
// Kernel 5: exact fp32 rescore, RP=8 points per block pass, coalesced embT4.
// ---------------------------------------------------------------------------
__global__ __launch_bounds__(256) void rescue_kernel(
    const float* __restrict__ x, const float4* __restrict__ embT4,
    const float* __restrict__ bias, const int* __restrict__ list,
    const int* __restrict__ counter, int* __restrict__ codes_i,
    float* __restrict__ codes_f)
{
    __shared__ float xv[RP][256];
    __shared__ int plist[RP];
    __shared__ float rs[RP][4];
    __shared__ int   rk[RP][4];
    const int tid = threadIdx.x, lane = tid & 63, wid = tid >> 6;
    const int count = *counter;
    for (int base = blockIdx.x * RP; base < count; base += gridDim.x * RP) {
        const int npts = min(RP, count - base);
        __syncthreads();   // protect LDS from previous iteration's readers
        if (tid < npts) plist[tid] = list[base + tid];
        __syncthreads();
        for (int pi = 0; pi < npts; ++pi) {
            const int p = plist[pi];
            xv[pi][tid] = x[((size_t)((p >> 12) * Dn + tid)) * Tn + (p & 4095)];
        }
        for (int pi = npts; pi < RP; ++pi) xv[pi][tid] = 0.f;
        __syncthreads();

        float acc[8][RP];
        #pragma unroll
        for (int s = 0; s < 8; ++s)
            #pragma unroll
            for (int pi = 0; pi < RP; ++pi) acc[s][pi] = 0.f;

        for (int dc = 0; dc < 64; ++dc) {
            float4 ev[8];
            #pragma unroll
            for (int s = 0; s < 8; ++s)
                ev[s] = embT4[(size_t)dc * Kn + tid + (s << 8)];   // coalesced
            #pragma unroll
            for (int pi = 0; pi < RP; ++pi) {
                const float4 xw = *(const float4*)&xv[pi][dc << 2];
                #pragma unroll
                for (int s = 0; s < 8; ++s)
                    acc[s][pi] += ev[s].x * xw.x + ev[s].y * xw.y
                                + ev[s].z * xw.z + ev[s].w * xw.w;
            }
        }

        float bs[RP]; int bk[RP];
        #pragma unroll
        for (int pi = 0; pi < RP; ++pi) { bs[pi] = -INFINITY; bk[pi] = 0; }
        #pragma unroll
        for (int s = 0; s < 8; ++s) {
            const int kk = tid + (s << 8);           // ascending per thread
            const float bv = bias[kk];
            #pragma unroll
            for (int pi = 0; pi < RP; ++pi) {
                const float sc = acc[s][pi] - bv;
                if (sc > bs[pi]) { bs[pi] = sc; bk[pi] = kk; }
            }
        }
        #pragma unroll
        for (int off = 1; off < 64; off <<= 1) {
            #pragma unroll
            for (int pi = 0; pi < RP; ++pi) {
                const float os = __shfl_xor(bs[pi], off);
                const int   ok = __shfl_xor(bk[pi], off);
                if (os > bs[pi] || (os == bs[pi] && ok < bk[pi])) { bs[pi] = os; bk[pi] = ok; }
            }
        }
        if (lane == 0) {
            #pragma unroll
            for (int pi = 0; pi < RP; ++pi) { rs[pi][wid] = bs[pi]; rk[pi][wid] = bk[pi]; }
        }
        __syncthreads();
        if (tid < npts) {
            float fs = rs[tid][0]; int fk = rk[tid][0];
            #pragma unroll
            for (int w = 1; w < 4; ++w) {
                if (rs[tid][w] > fs || (rs[tid][w] == fs && rk[tid][w] < fk)) {
                    fs = rs[tid][w]; fk = rk[tid][w];
                }
            }
            const int p = plist[tid];
            codes_i[p] = fk;
            codes_f[p] = (float)fk;
        }
    }
}

// ---------------------------------------------------------------------------
// Kernel 6: decode — decoded[b,d,t] = emb[codes[b,t]][d]
// ---------------------------------------------------------------------------
__global__ __launch_bounds__(256) void decode_kernel(
    const float* __restrict__ emb, const int* __restrict__ codes,
    float* __restrict__ out)
{
    const int b = blockIdx.y;
    const int t = blockIdx.x * 256 + threadIdx.x;
    const int c = codes[(size_t)b * Tn + t];
    const float4* e4 = (const float4*)(emb + (size_t)c * Dn);
    float* ob = out + (size_t)b * Dn * Tn + t;
    #pragma unroll 4
    for (int d4 = 0; d4 < 64; ++d4) {
        const float4 v = e4[d4];
        ob[(size_t)(d4 * 4 + 0) * Tn] = v.x;
        ob[(size_t)(d4 * 4 + 1) * Tn] = v.y;
        ob[(size_t)(d4 * 4 + 2) * Tn] = v.z;
        ob[(size_t)(d4 * 4 + 3) * Tn] = v.w;
    }
}

// ---------------------------------------------------------------------------
extern "C" void kernel_launch(void* const* d_in, const int* in_sizes, int n_in,
                              void* d_out, int out_size, void* d_ws, size_t ws_size,
                              hipStream_t stream) {
    const float* x     = (const float*)d_in[0];   // [B, D, T]
    const float* es    = (const float*)d_in[1];   // [K, D]
    const float* usage = (const float*)d_in[2];   // [K]

    // ws layout (byte offsets, 16-aligned) — ~10.5 MiB (< proven 13.1 MiB)
    char* ws = (char*)d_ws;
    float*    emb     = (float*)(ws + 0);                // 2 MiB
    float*    bias    = (float*)(ws + 2097152);          // 8 KB
    ushort_t* eh      = (ushort_t*)(ws + 2105344);       // 1 MiB
    ushort_t* em      = (ushort_t*)(ws + 3153920);       // 1 MiB
    float4*   embT4   = (float4*)(ws + 4202496);         // 2 MiB
    uint2*    rec     = (uint2*)(ws + 6299648);          // 4 MiB (8 x 65536 x 8B)
    int*      codes_i = (int*)(ws + 10493952);           // 256 KB
    int*      list    = (int*)(ws + 10756096);           // 256 KB
    int*      counter = (int*)(ws + 11018240);           // 4 B

    float* codes_f = (float*)d_out;                      // [B*T]
    float* decoded = (float*)d_out + (size_t)Bn * Tn;    // [B*D*T], 64 MiB

    // xh lives in the decoded region (32 of 64 MiB); decode overwrites last.
    ushort_t* xh = (ushort_t*)decoded;                   // 32 MiB

    prep_kernel<<<Kn, 256, 0, stream>>>(es, usage, emb, eh, em, bias, embT4, counter);

    dim3 gx(Tn / 16, Bn);
    xsplit_kernel<<<gx, 256, 0, stream>>>(x, xh);

    gemm_argmax<<<4096, 256, 0, stream>>>(xh, eh, em, bias, rec);

    merge_kernel<<<(Bn * Tn) / 256, 256, 0, stream>>>(rec, codes_i, codes_f, list, counter);

    rescue_kernel<<<1024, 256, 0, stream>>>(x, embT4, bias, list, counter, codes_i, codes_f);

    dim3 g6(Tn / 256, Bn);
    decode_kernel<<<g6, 256, 0, stream>>>(emb, codes_i, decoded);
}

// Round 7
// 359.796 us; speedup vs baseline: 5.0864x; 1.3187x over previous
//
#include <hip/hip_runtime.h>
#include <hip/hip_fp16.h>
#include <cmath>

#define EPS 1e-5f
#define TAU 0.15f
#define RP  8

// Problem constants (fixed instance)
#define Bn 16
#define Dn 256
#define Tn 4096
#define Kn 2048

typedef unsigned short ushort_t;
typedef __attribute__((ext_vector_type(8))) _Float16 f16x8;
typedef __attribute__((ext_vector_type(4))) float f32x4;

__device__ __forceinline__ unsigned short f2h(float v) {
    return __half_as_ushort(__float2half_rn(v));
}

// fp16 rounded UP in value (result >= v). ulp <= 0.125 for |v| < 256.
__device__ __forceinline__ unsigned short f16_up(float v) {
    const __half h = __float2half_rn(v);
    const float back = __half2float(h);
    unsigned short u = __half_as_ushort(h);
    if (back < v) u = (u & 0x8000u) ? (u - 1) : (u + 1);
    return u;
}

#define GLOAD_LDS16(gp, lp) __builtin_amdgcn_global_load_lds( \
    (const __attribute__((address_space(1))) unsigned int*)(gp), \
    (__attribute__((address_space(3))) unsigned int*)(lp), 16, 0, 0)

// ---------------------------------------------------------------------------
// Kernel 1: prep — emb = es/max(usage,eps); e16 fp16 plane (clamped; huge-|e|
// rows can't win since bias uses exact emb); bias = 0.5|e|^2; embT4 transpose.
// ---------------------------------------------------------------------------
__global__ __launch_bounds__(256) void prep_kernel(
    const float* __restrict__ es, const float* __restrict__ usage,
    float* __restrict__ emb, ushort_t* __restrict__ e16,
    float* __restrict__ bias, float4* __restrict__ embT4,
    int* __restrict__ counter)
{
    __shared__ float sh[256];
    __shared__ float wsum[4];
    const int k = blockIdx.x;
    const int d = threadIdx.x;
    const float inv = 1.0f / fmaxf(usage[k], EPS);
    const float v = es[(size_t)k * Dn + d] * inv;
    emb[(size_t)k * Dn + d] = v;
    e16[(size_t)k * Dn + d] = f2h(fminf(fmaxf(v, -65504.f), 65504.f));
    sh[d] = v;
    float sq = v * v;
    #pragma unroll
    for (int off = 32; off > 0; off >>= 1) sq += __shfl_down(sq, off, 64);
    const int lane = d & 63, wv = d >> 6;
    if (lane == 0) wsum[wv] = sq;
    __syncthreads();
    if (d < 64)
        embT4[(size_t)d * Kn + k] = make_float4(sh[4*d], sh[4*d+1], sh[4*d+2], sh[4*d+3]);
    if (d == 0) {
        bias[k] = 0.5f * (wsum[0] + wsum[1] + wsum[2] + wsum[3]);
        if (k == 0) *counter = 0;
    }
}

// ---------------------------------------------------------------------------
// Kernel 2: xsplit — x[b][d][t] fp32 -> xh[b][t][d] fp16.
// Tile 32d x 64t (R2 mapping: contiguous-t reads); LDS transpose, +1 pad.
// ---------------------------------------------------------------------------
__global__ __launch_bounds__(256) void xsplit_kernel(
    const float* __restrict__ x, ushort_t* __restrict__ xh)
{
    __shared__ float tile[32 * 65];
    const int t0 = blockIdx.x * 64;
    const int d0 = blockIdx.y * 32;
    const int b  = blockIdx.z;
    const int tid = threadIdx.x;

    // read: (dl, tq) — 8 floats along t per thread; 128 B contiguous per dl
    {
        const int dl = tid >> 3, tq = tid & 7;
        const float* src = x + ((size_t)(b * Dn + d0 + dl)) * Tn + t0 + tq * 8;
        const float4 a = *(const float4*)(src);
        const float4 c = *(const float4*)(src + 4);
        float* row = &tile[dl * 65 + tq * 8];
        row[0] = a.x; row[1] = a.y; row[2] = a.z; row[3] = a.w;
        row[4] = c.x; row[5] = c.y; row[6] = c.z; row[7] = c.w;
    }
    __syncthreads();
    // write: (t_l, dq) — 8 d-consecutive fp16 -> one 16 B store
    {
        const int t_l = tid >> 2, dq = tid & 3;
        unsigned wh[4];
        #pragma unroll
        for (int i = 0; i < 4; ++i) {
            const float a = tile[(dq * 8 + 2 * i) * 65 + t_l];
            const float g = tile[(dq * 8 + 2 * i + 1) * 65 + t_l];
            wh[i] = (unsigned)f2h(a) | ((unsigned)f2h(g) << 16);
        }
        const size_t o = ((size_t)(b * Tn + t0 + t_l)) * Dn + d0 + dq * 8;
        *(uint4*)(xh + o) = make_uint4(wh[0], wh[1], wh[2], wh[3]);
    }
}

// ---------------------------------------------------------------------------
// Kernel 3: single-product fp16 MFMA GEMM + top-2 argmax.  s ~= xh16 . e16.
// R3 structure: wave-tile 32t x 128k (2 i-tiles x 8 j), KSPLIT=8
// (256 k/block, 2 kc), BK=32. Running per-lane top-2 in REGISTERS across
// both kc; ONE butterfly at kernel end (the per-kc butterfly was R4-R6's
// VALU/LDS regression). 2 LDS planes only. Record: 8 B slot-major.
// ---------------------------------------------------------------------------
__global__ __launch_bounds__(256, 4) void gemm_argmax(
    const ushort_t* __restrict__ xh, const ushort_t* __restrict__ e16,
    const float* __restrict__ bias, uint2* __restrict__ rec)
{
    __shared__ ushort_t AhS[128 * 32];   // 8 KB [t][d32]
    __shared__ ushort_t BhS[128 * 32];   // 8 KB [k][d32]

    const int bid   = blockIdx.x;
    const int xcd   = bid & 7;
    const int ks    = (bid >> 3) & 7;
    const int tilid = bid >> 6;
    const int gtile = tilid * 8 + xcd;   // ks-siblings of one (b,tt) share an XCD
    const int b     = gtile >> 5;
    const int tt    = gtile & 31;
    const int t0    = tt << 7;
    const int kbase = ks << 8;

    const int tid  = threadIdx.x;
    const int lane = tid & 63;
    const int wid  = tid >> 6;
    const int l15  = lane & 15;
    const int quad = lane >> 4;

    const size_t bTt0 = (size_t)b * Tn + t0;

    const int aoff0 = (wid * 32 + l15) * 32 + quad * 8;
    const int aoff1 = aoff0 + 16 * 32;
    const int boffL = l15 * 32 + quad * 8;

    float s1[8], s2[8];
    int   k1[8];
    #pragma unroll
    for (int rr = 0; rr < 8; ++rr) { s1[rr] = -INFINITY; s2[rr] = -INFINITY; k1[rr] = 0; }

    for (int kc = 0; kc < 2; ++kc) {
        const int k0 = kbase + kc * 128;

        f32x4 acc[2][8];
        #pragma unroll
        for (int i = 0; i < 2; ++i)
            #pragma unroll
            for (int j = 0; j < 8; ++j) acc[i][j] = (f32x4){0.f, 0.f, 0.f, 0.f};

        for (int dstep = 0; dstep < 8; ++dstep) {
            const int d0 = dstep * 32;
            __syncthreads();   // previous stage's readers done

            #pragma unroll
            for (int r = 0; r < 2; ++r) {
                const int cb = (r * 4 + wid) << 6;     // wave-uniform chunk base
                const int c  = cb + lane;              // 0..511
                const int row = c >> 2;
                const int doff = d0 + (c & 3) * 8;
                const size_t ao = (bTt0 + row) * Dn + doff;
                const size_t bo = ((size_t)(k0 + row)) * Dn + doff;
                const int lb = cb * 8;                 // shorts
                GLOAD_LDS16(xh + ao, AhS + lb);
                GLOAD_LDS16(e16 + bo, BhS + lb);
            }
            __syncthreads();   // barrier drains vmcnt

            const f16x8 ah0 = *(const f16x8*)(AhS + aoff0);
            const f16x8 ah1 = *(const f16x8*)(AhS + aoff1);
            #pragma unroll
            for (int j = 0; j < 8; ++j) {
                const f16x8 bh = *(const f16x8*)(BhS + (j << 9) + boffL);
                acc[0][j] = __builtin_amdgcn_mfma_f32_16x16x32_f16(ah0, bh, acc[0][j], 0, 0, 0);
                acc[1][j] = __builtin_amdgcn_mfma_f32_16x16x32_f16(ah1, bh, acc[1][j], 0, 0, 0);
            }
        }

        // epilogue: bias + running top-2 in registers (k ascending: j, then kc)
        #pragma unroll
        for (int j = 0; j < 8; ++j) {
            const int kg = k0 + j * 16 + l15;
            const float bj = bias[kg];
            #pragma unroll
            for (int i = 0; i < 2; ++i) {
                #pragma unroll
                for (int r = 0; r < 4; ++r) {
                    const float s = acc[i][j][r] - bj;
                    const int rr = i * 4 + r;
                    if (s > s1[rr]) { s2[rr] = s1[rr]; s1[rr] = s; k1[rr] = kg; }
                    else if (s > s2[rr]) s2[rr] = s;
                }
            }
        }
    }

    // ONE butterfly merge across the 16 lanes sharing each t-row
    #pragma unroll
    for (int m = 1; m <= 8; m <<= 1) {
        #pragma unroll
        for (int rr = 0; rr < 8; ++rr) {
            const float os1 = __shfl_xor(s1[rr], m);
            const float os2 = __shfl_xor(s2[rr], m);
            const int   ok1 = __shfl_xor(k1[rr], m);
            const bool take = (os1 > s1[rr]) || (os1 == s1[rr] && ok1 < k1[rr]);
            const float ns2 = take ? fmaxf(s1[rr], os2) : fmaxf(s2[rr], os1);
            if (take) { s1[rr] = os1; k1[rr] = ok1; }
            s2[rr] = ns2;
        }
    }

    if (l15 == 0) {
        #pragma unroll
        for (int rr = 0; rr < 8; ++rr) {
            const int i = rr >> 2, r = rr & 3;
            const int row = wid * 32 + i * 16 + quad * 4 + r;
            uint2 e;
            e.x = __float_as_uint(s1[rr]);
            e.y = ((unsigned)f16_up(s2[rr]) << 16) | (unsigned)k1[rr];
            rec[(size_t)ks * (Bn * Tn) + bTt0 + row] = e;
        }
    }
}

// ---------------------------------------------------------------------------
// Kernel 4: merge 8 slot-major records per point; codes + rescue list.
// Non-winner slots contribute exact fp32 s1; winner's s2 is fp16-up bound.
// ---------------------------------------------------------------------------
__global__ __launch_bounds__(256) void merge_kernel(
    const uint2* __restrict__ rec, int* __restrict__ codes_i,
    float* __restrict__ codes_f, int* __restrict__ list, int* __restrict__ counter)
{
    const int p = blockIdx.x * 256 + threadIdx.x;
    uint2 e = rec[p];
    float g1 = __uint_as_float(e.x);
    float g2 = __half2float(__ushort_as_half((unsigned short)(e.y >> 16)));
    int kk = (int)(e.y & 0xffffu);
    #pragma unroll
    for (int s = 1; s < 8; ++s) {                     // slots ascending in k
        e = rec[(size_t)s * (Bn * Tn) + p];
        const float s1 = __uint_as_float(e.x);
        if (s1 > g1) {
            const float s2u = __half2float(__ushort_as_half((unsigned short)(e.y >> 16)));
            g2 = fmaxf(fmaxf(g2, g1), s2u);
            g1 = s1;
            kk = (int)(e.y & 0xffffu);
        } else {
            g2 = fmaxf(g2, s1);
        }
    }
    codes_i[p] = kk;
    codes_f[p] = (float)kk;
    if (g1 - g2 < TAU) {
        const int idx = atomicAdd(counter, 1);
        list[idx] = p;
    }
}

// ---------------------------------------------------------------------------
// Kernel 5: exact fp32 rescore, RP=8 points per block pass, coalesced embT4.
// ---------------------------------------------------------------------------
__global__ __launch_bounds__(256) void rescue_kernel(
    const float* __restrict__ x, const float4* __restrict__ embT4,
    const float* __restrict__ bias, const int* __restrict__ list,
    const int* __restrict__ counter, int* __restrict__ codes_i,
    float* __restrict__ codes_f)
{
    __shared__ float xv[RP][256];
    __shared__ int plist[RP];
    __shared__ float rs[RP][4];
    __shared__ int   rk[RP][4];
    const int tid = threadIdx.x, lane = tid & 63, wid = tid >> 6;
    const int count = *counter;
    for (int base = blockIdx.x * RP; base < count; base += gridDim.x * RP) {
        const int npts = min(RP, count - base);
        __syncthreads();   // protect LDS from previous iteration's readers
        if (tid < npts) plist[tid] = list[base + tid];
        __syncthreads();
        for (int pi = 0; pi < npts; ++pi) {
            const int p = plist[pi];
            xv[pi][tid] = x[((size_t)((p >> 12) * Dn + tid)) * Tn + (p & 4095)];
        }
        for (int pi = npts; pi < RP; ++pi) xv[pi][tid] = 0.f;
        __syncthreads();

        float acc[8][RP];
        #pragma unroll
        for (int s = 0; s < 8; ++s)
            #pragma unroll
            for (int pi = 0; pi < RP; ++pi) acc[s][pi] = 0.f;

        for (int dc = 0; dc < 64; ++dc) {
            float4 ev[8];
            #pragma unroll
            for (int s = 0; s < 8; ++s)
                ev[s] = embT4[(size_t)dc * Kn + tid + (s << 8)];   // coalesced
            #pragma unroll
            for (int pi = 0; pi < RP; ++pi) {
                const float4 xw = *(const float4*)&xv[pi][dc << 2];
                #pragma unroll
                for (int s = 0; s < 8; ++s)
                    acc[s][pi] += ev[s].x * xw.x + ev[s].y * xw.y
                                + ev[s].z * xw.z + ev[s].w * xw.w;
            }
        }

        float bs[RP]; int bk[RP];
        #pragma unroll
        for (int pi = 0; pi < RP; ++pi) { bs[pi] = -INFINITY; bk[pi] = 0; }
        #pragma unroll
        for (int s = 0; s < 8; ++s) {
            const int kk = tid + (s << 8);           // ascending per thread
            const float bv = bias[kk];
            #pragma unroll
            for (int pi = 0; pi < RP; ++pi) {
                const float sc = acc[s][pi] - bv;
                if (sc > bs[pi]) { bs[pi] = sc; bk[pi] = kk; }
            }
        }
        #pragma unroll
        for (int off = 1; off < 64; off <<= 1) {
            #pragma unroll
            for (int pi = 0; pi < RP; ++pi) {
                const float os = __shfl_xor(bs[pi], off);
                const int   ok = __shfl_xor(bk[pi], off);
                if (os > bs[pi] || (os == bs[pi] && ok < bk[pi])) { bs[pi] = os; bk[pi] = ok; }
            }
        }
        if (lane == 0) {
            #pragma unroll
            for (int pi = 0; pi < RP; ++pi) { rs[pi][wid] = bs[pi]; rk[pi][wid] = bk[pi]; }
        }
        __syncthreads();
        if (tid < npts) {
            float fs = rs[tid][0]; int fk = rk[tid][0];
            #pragma unroll
            for (int w = 1; w < 4; ++w) {
                if (rs[tid][w] > fs || (rs[tid][w] == fs && rk[tid][w] < fk)) {
                    fs = rs[tid][w]; fk = rk[tid][w];
                }
            }
            const int p = plist[tid];
            codes_i[p] = fk;
            codes_f[p] = (float)fk;
        }
    }
}

// ---------------------------------------------------------------------------
// Kernel 6: decode — decoded[b,d,t] = emb[codes[b,t]][d]
// ---------------------------------------------------------------------------
__global__ __launch_bounds__(256) void decode_kernel(
    const float* __restrict__ emb, const int* __restrict__ codes,
    float* __restrict__ out)
{
    const int b = blockIdx.y;
    const int t = blockIdx.x * 256 + threadIdx.x;
    const int c = codes[(size_t)b * Tn + t];
    const float4* e4 = (const float4*)(emb + (size_t)c * Dn);
    float* ob = out + (size_t)b * Dn * Tn + t;
    #pragma unroll 4
    for (int d4 = 0; d4 < 64; ++d4) {
        const float4 v = e4[d4];
        ob[(size_t)(d4 * 4 + 0) * Tn] = v.x;
        ob[(size_t)(d4 * 4 + 1) * Tn] = v.y;
        ob[(size_t)(d4 * 4 + 2) * Tn] = v.z;
        ob[(size_t)(d4 * 4 + 3) * Tn] = v.w;
    }
}

// ---------------------------------------------------------------------------
extern "C" void kernel_launch(void* const* d_in, const int* in_sizes, int n_in,
                              void* d_out, int out_size, void* d_ws, size_t ws_size,
                              hipStream_t stream) {
    const float* x     = (const float*)d_in[0];   // [B, D, T]
    const float* es    = (const float*)d_in[1];   // [K, D]
    const float* usage = (const float*)d_in[2];   // [K]

    // ws layout (byte offsets, 16-aligned) — ~6 MiB
    char* ws = (char*)d_ws;
    float*    emb     = (float*)(ws + 0);                // 2 MiB
    float*    bias    = (float*)(ws + 2097152);          // 8 KB
    ushort_t* e16     = (ushort_t*)(ws + 2105344);       // 1 MiB
    float4*   embT4   = (float4*)(ws + 3153920);         // 2 MiB
    int*      codes_i = (int*)(ws + 5251072);            // 256 KB
    int*      list    = (int*)(ws + 5513216);            // 256 KB
    int*      counter = (int*)(ws + 5775360);            // 4 B

    float* codes_f = (float*)d_out;                      // [B*T]
    float* decoded = (float*)d_out + (size_t)Bn * Tn;    // [B*D*T], 64 MiB

    // xh (fp16, 32 MiB) and rec (4 MiB) live inside the decoded region;
    // decode overwrites at the very end, after both are consumed.
    ushort_t* xh  = (ushort_t*)decoded;                            // 32 MiB
    uint2*    rec = (uint2*)((char*)decoded + 33554432);           // 4 MiB

    prep_kernel<<<Kn, 256, 0, stream>>>(es, usage, emb, e16, bias, embT4, counter);

    dim3 gx(Tn / 64, Dn / 32, Bn);
    xsplit_kernel<<<gx, 256, 0, stream>>>(x, xh);

    gemm_argmax<<<4096, 256, 0, stream>>>(xh, e16, bias, rec);

    merge_kernel<<<(Bn * Tn) / 256, 256, 0, stream>>>(rec, codes_i, codes_f, list, counter);

    rescue_kernel<<<1024, 256, 0, stream>>>(x, embT4, bias, list, counter, codes_i, codes_f);

    dim3 g6(Tn / 256, Bn);
    decode_kernel<<<g6, 256, 0, stream>>>(emb, codes_i, decoded);
}